// Round 17
// baseline (1128.701 us; speedup 1.0000x reference)
//
#include <hip/hip_runtime.h>
#include <hip/hip_bf16.h>
#include <cstdint>
#include <cstddef>

namespace {

constexpr int kN = 50000;   // nodes
constexpr int kE = 800000;  // edges
constexpr int kPl = 3200000;  // plane elements (kN*64)
constexpr float kInv3 = 0.57735026918962576451f; // 1/sqrt(3)
constexpr float kInv2 = 0.70710678118654752440f; // 1/sqrt(2)

typedef __attribute__((ext_vector_type(8))) short bf16x8;
typedef __attribute__((ext_vector_type(4))) float f32x4;
union FragU { uint32_t u[4]; bf16x8 v; uint4 q; };

__device__ __forceinline__ float bcast(float v, int k) {
  return __int_as_float(__builtin_amdgcn_readlane(__float_as_int(v), k));
}
__device__ __forceinline__ int bcasti(int v, int k) {
  return __builtin_amdgcn_readlane(v, k);
}
__device__ __forceinline__ float silu(float x) {
  return x / (1.0f + __expf(-x));
}
__device__ __forceinline__ uint32_t bf16r(float f) {  // RTNE
  uint32_t u = __float_as_uint(f);
  return (u + 0x7fffu + ((u >> 16) & 1u)) >> 16;
}
__device__ __forceinline__ float blo(uint32_t u) { return __uint_as_float(u << 16); }
__device__ __forceinline__ float bhi(uint32_t u) { return __uint_as_float(u & 0xffff0000u); }
__device__ __forceinline__ uint32_t pk(float a, float b) {
  union { __hip_bfloat16 h; unsigned short s; } x, y;
  x.h = __float2bfloat16(a);
  y.h = __float2bfloat16(b);
  return (uint32_t)x.s | ((uint32_t)y.s << 16);
}

// ---------------------------------------------------------------------------
// K1: h0 = x0 @ pre_W0 ; h1[:,:,m] = x1[:,:,m] @ pre_W1
// h output packed bf16x4 (uint2/lane). Also emits planar bf16 x1 (xp).
// ---------------------------------------------------------------------------
__global__ __launch_bounds__(256) void k_pre(const float* __restrict__ nf,
                                             const float* __restrict__ W0,
                                             const float* __restrict__ W1,
                                             uint2* __restrict__ hq,
                                             unsigned short* __restrict__ xp) {
  __shared__ float sW[8192];
  __shared__ float sbuf[4][256];
  for (int i = threadIdx.x; i < 8192; i += 256)
    sW[i] = (i < 4096) ? W0[i] : W1[i - 4096];
  __syncthreads();

  const int wid = threadIdx.x >> 6, lane = threadIdx.x & 63;
  for (int nb = blockIdx.x * 4; nb < kN; nb += 2048 * 4) {
    const int n = nb + wid;
    if (n >= kN) continue;
    const float4 rv = ((const float4*)nf)[(size_t)n * 64 + lane];
    *(float4*)&sbuf[wid][lane * 4] = rv;
    const float v0 = sbuf[wid][lane];
    const float vx = sbuf[wid][64 + 3 * lane];
    const float vy = sbuf[wid][64 + 3 * lane + 1];
    const float vz = sbuf[wid][64 + 3 * lane + 2];
    xp[(size_t)n * 64 + lane] = (unsigned short)bf16r(vx);
    xp[(size_t)kPl + (size_t)n * 64 + lane] = (unsigned short)bf16r(vy);
    xp[(size_t)2 * kPl + (size_t)n * 64 + lane] = (unsigned short)bf16r(vz);
    float a0 = 0.f, ax = 0.f, ay = 0.f, az = 0.f;
#pragma unroll
    for (int k = 0; k < 64; ++k) {
      const float w0 = sW[k * 64 + lane];
      const float w1 = sW[4096 + k * 64 + lane];
      a0 = fmaf(bcast(v0, k), w0, a0);
      ax = fmaf(bcast(vx, k), w1, ax);
      ay = fmaf(bcast(vy, k), w1, ay);
      az = fmaf(bcast(vz, k), w1, az);
    }
    uint2 hv;
    hv.x = pk(a0, ax);
    hv.y = pk(ay, az);
    hq[(size_t)n * 64 + lane] = hv;
  }
}

// ---------------------------------------------------------------------------
// CSR build
// ---------------------------------------------------------------------------
__global__ void k_hist(const int* __restrict__ ei, int* __restrict__ cnt) {
  const int e = blockIdx.x * blockDim.x + threadIdx.x;
  if (e < kE) atomicAdd(&cnt[ei[kE + e]], 1);
}

__global__ __launch_bounds__(1024) void k_scan(const int* __restrict__ cnt,
                                               int* __restrict__ starts) {
  __shared__ int sh[1024];
  const int t = threadIdx.x;
  constexpr int CH = 49;
  const int base = t * CH;
  int s = 0;
  for (int i = 0; i < CH; ++i) {
    const int idx = base + i;
    if (idx < kN) s += cnt[idx];
  }
  sh[t] = s;
  __syncthreads();
  for (int off = 1; off < 1024; off <<= 1) {
    const int v = sh[t];
    const int o = (t >= off) ? sh[t - off] : 0;
    __syncthreads();
    sh[t] = v + o;
    __syncthreads();
  }
  int run = sh[t] - s;
  for (int i = 0; i < CH; ++i) {
    const int idx = base + i;
    if (idx < kN) {
      starts[idx] = run;
      run += cnt[idx];
    }
  }
}

__global__ void k_scatter(const int* __restrict__ ei, int* __restrict__ cursor,
                          int* __restrict__ eids) {
  const int e = blockIdx.x * blockDim.x + threadIdx.x;
  if (e < kE) {
    const int pos = atomicAdd(&cursor[ei[kE + e]], 1);
    eids[pos] = e;
  }
}

// ---------------------------------------------------------------------------
// K2a (MFMA): per-wave 16-edge tile runs the radial MLP as 3 chained GEMMs.
// (R8-verified; grid widened to 1536 for tail balance)
// ---------------------------------------------------------------------------
__device__ __forceinline__ void xpose(const uint32_t* pa, const uint32_t* pb,
                                      int addr0, int addr1, bool ghi,
                                      FragU* out) {
#pragma unroll
  for (int kt = 0; kt < 2; ++kt) {
    const int m0 = 2 * kt, m1 = 2 * kt + 1;
    int t0, t1;
    t0 = __builtin_amdgcn_ds_bpermute(addr0, (int)pa[m0]);
    t1 = __builtin_amdgcn_ds_bpermute(addr0, (int)pa[m1]);
    out[kt].u[0] = (uint32_t)(ghi ? t1 : t0);
    t0 = __builtin_amdgcn_ds_bpermute(addr0, (int)pb[m0]);
    t1 = __builtin_amdgcn_ds_bpermute(addr0, (int)pb[m1]);
    out[kt].u[1] = (uint32_t)(ghi ? t1 : t0);
    t0 = __builtin_amdgcn_ds_bpermute(addr1, (int)pa[m0]);
    t1 = __builtin_amdgcn_ds_bpermute(addr1, (int)pa[m1]);
    out[kt].u[2] = (uint32_t)(ghi ? t1 : t0);
    t0 = __builtin_amdgcn_ds_bpermute(addr1, (int)pb[m0]);
    t1 = __builtin_amdgcn_ds_bpermute(addr1, (int)pb[m1]);
    out[kt].u[3] = (uint32_t)(ghi ? t1 : t0);
  }
}

__global__ __launch_bounds__(256, 2) void k_mlp(
    const float* __restrict__ rb, const int* __restrict__ eids,
    const float* __restrict__ W1f, const float* __restrict__ W2f,
    const float* __restrict__ W3f, uint32_t* __restrict__ wout,
    int tile0, int ntiles) {
  __shared__ uint32_t sfrag[13312];  // 52 frags x 256 u32
  for (int i = threadIdx.x; i < 13312; i += 256) {
    const int f = i >> 8, l = (i >> 2) & 63, jp = i & 3;
    const int kk = ((l >> 4) << 3) + 2 * jp;
    float a, b;
    if (f < 4) {  // W1^T, K padded 8->32 with zeros
      const int c = (f << 4) + (l & 15);
      a = (kk < 8) ? W1f[kk * 64 + c] : 0.f;
      b = (kk < 7) ? W1f[(kk + 1) * 64 + c] : 0.f;
    } else if (f < 12) {  // W2^T: frag (kt, mt)
      const int kt = (f - 4) >> 2, mt = (f - 4) & 3;
      const int k = kt * 32 + kk, c = (mt << 4) + (l & 15);
      a = W2f[k * 64 + c];
      b = W2f[(k + 1) * 64 + c];
    } else {  // W3^T: frag (kt, mt), mt 0..19
      const int kt = (f - 12) / 20, mt = (f - 12) % 20;
      const int k = kt * 32 + kk, c = (mt << 4) + (l & 15);
      a = W3f[k * 320 + c];
      b = W3f[(k + 1) * 320 + c];
    }
    sfrag[i] = pk(a, b);
  }
  __syncthreads();

  const int lane = threadIdx.x & 63;
  const int e15 = lane & 15, g = lane >> 4;
  const uint4* fr = (const uint4*)sfrag;
  const int wv = blockIdx.x * 4 + (threadIdx.x >> 6);
  const int addr0 = ((((g & 1) << 1)) * 16 + e15) * 4;
  const int addr1 = addr0 + 64;
  const bool ghi = (g >> 1) != 0;
  const f32x4 z = {0.f, 0.f, 0.f, 0.f};

  for (int t = wv; t < ntiles; t += 1536 * 4) {
    FragU b1;
    b1.u[0] = b1.u[1] = b1.u[2] = b1.u[3] = 0;
    if (lane < 16) {
      const int e = eids[(size_t)(tile0 + t) * 16 + lane];
      const float4 r0 = *(const float4*)(rb + (size_t)e * 8);
      const float4 r1 = *(const float4*)(rb + (size_t)e * 8 + 4);
      b1.u[0] = pk(r0.x, r0.y);
      b1.u[1] = pk(r0.z, r0.w);
      b1.u[2] = pk(r1.x, r1.y);
      b1.u[3] = pk(r1.z, r1.w);
    }

    uint32_t pa[4], pb[4];
#pragma unroll
    for (int mt = 0; mt < 4; ++mt) {
      FragU a;
      a.q = fr[(mt << 6) + lane];
      f32x4 d = __builtin_amdgcn_mfma_f32_16x16x32_bf16(a.v, b1.v, z, 0, 0, 0);
      pa[mt] = pk(silu(d[0]), silu(d[1]));
      pb[mt] = pk(silu(d[2]), silu(d[3]));
    }
    FragU b2[2];
    xpose(pa, pb, addr0, addr1, ghi, b2);

    f32x4 d2[4] = {z, z, z, z};
#pragma unroll
    for (int kt = 0; kt < 2; ++kt)
#pragma unroll
      for (int mt = 0; mt < 4; ++mt) {
        FragU a;
        a.q = fr[((4 + kt * 4 + mt) << 6) + lane];
        d2[mt] =
            __builtin_amdgcn_mfma_f32_16x16x32_bf16(a.v, b2[kt].v, d2[mt], 0, 0, 0);
      }
#pragma unroll
    for (int mt = 0; mt < 4; ++mt) {
      pa[mt] = pk(silu(d2[mt][0]), silu(d2[mt][1]));
      pb[mt] = pk(silu(d2[mt][2]), silu(d2[mt][3]));
    }
    FragU b3[2];
    xpose(pa, pb, addr0, addr1, ghi, b3);

    uint32_t* wt = wout + (size_t)t * 2560 + lane;
#pragma unroll 4
    for (int mt = 0; mt < 20; ++mt) {
      FragU a0, a1;
      a0.q = fr[((12 + mt) << 6) + lane];
      a1.q = fr[((32 + mt) << 6) + lane];
      f32x4 d = __builtin_amdgcn_mfma_f32_16x16x32_bf16(a0.v, b3[0].v, z, 0, 0, 0);
      d = __builtin_amdgcn_mfma_f32_16x16x32_bf16(a1.v, b3[1].v, d, 0, 0, 0);
      wt[mt * 128] = pk(d[0], d[1]);
      wt[mt * 128 + 64] = pk(d[2], d[3]);
    }
  }
}

// ---------------------------------------------------------------------------
// K2b: slim consumer over slot range [lo, hi). bf16 h rows; tcomb stored as
// bf16x4 (uint2) RMW — halves the accumulate traffic. Grid 1024 for tail.
// ---------------------------------------------------------------------------
__global__ __launch_bounds__(1024, 6) void k_edge2(
    const float* __restrict__ sph, const int* __restrict__ ei,
    const int* __restrict__ eids, const int* __restrict__ ends,
    const int* __restrict__ cnts, const uint32_t* __restrict__ w32,
    const uint2* __restrict__ hq, uint2* __restrict__ tq,
    int lo, int hi) {
  const int lane = threadIdx.x & 63;
  const int LCb = ((lane >> 4) << 7) + (((lane & 3) >> 1) << 6) +
                  (((lane >> 2) & 3) << 4);
  const uint32_t shl = (lane & 1) ? 0u : 16u;
  const int gw = blockIdx.x * 16 + (threadIdx.x >> 6);
  for (int n = gw; n < kN; n += 1024 * 16) {
    int tmp = 0;
    if (lane == 0) tmp = ends[n];
    else if (lane == 1) tmp = cnts[n];
    const int end = bcasti(tmp, 0);
    const int cn = bcasti(tmp, 1);
    const int s0 = max(end - cn, lo);
    const int s1 = min(end, hi);
    if (s0 >= s1) continue;
    float a0 = 0.f, axx = 0.f, ayy = 0.f, azz = 0.f;

    for (int base = s0; base < s1; base += 64) {
      const int m = min(64, s1 - base);
      int sidv = 0;
      float4 svv = make_float4(0.f, 0.f, 0.f, 0.f);
      if (lane < m) {
        const int ev = eids[base + lane];
        sidv = ei[ev];
        svv = *(const float4*)(sph + (size_t)ev * 4);
      }
      // preload edge 0
      const int scur = bcasti(sidv, 0);
      uint2 hu = hq[(size_t)scur * 64 + lane];
      const int sl0 = base - lo;
      size_t wi = (size_t)(sl0 >> 4) * 2560 + (sl0 & 15) + LCb;
      uint32_t u0 = w32[wi], u1 = w32[wi + 512], u2 = w32[wi + 1024],
               u3 = w32[wi + 1536], u4 = w32[wi + 2048];

      for (int j = 0; j < m; ++j) {
        uint2 hn = hu;
        uint32_t n0 = u0, n1 = u1, n2 = u2, n3 = u3, n4 = u4;
        if (j + 1 < m) {
          const int sn = bcasti(sidv, j + 1);
          hn = hq[(size_t)sn * 64 + lane];
          const int sl = base + j + 1 - lo;
          const size_t wj = (size_t)(sl >> 4) * 2560 + (sl & 15) + LCb;
          n0 = w32[wj];
          n1 = w32[wj + 512];
          n2 = w32[wj + 1024];
          n3 = w32[wj + 1536];
          n4 = w32[wj + 2048];
        }
        const float y0 = bcast(svv.x, j), y1 = bcast(svv.y, j);
        const float y2 = bcast(svv.z, j), y3 = bcast(svv.w, j);
        const float hx = blo(hu.x), hy = bhi(hu.x);
        const float hz = blo(hu.y), hw = bhi(hu.y);
        const float w0 = __uint_as_float((u0 << shl) & 0xffff0000u);
        const float w1v = __uint_as_float((u1 << shl) & 0xffff0000u);
        const float w2v = __uint_as_float((u2 << shl) & 0xffff0000u);
        const float w3v = __uint_as_float((u3 << shl) & 0xffff0000u);
        const float w4v = __uint_as_float((u4 << shl) & 0xffff0000u);

        const float dot = hy * y1 + hz * y2 + hw * y3;
        const float m0 = w0 * hx * y0 + w1v * kInv3 * dot;
        const float cx = hz * y3 - hw * y2;
        const float cy = hw * y1 - hy * y3;
        const float cz = hy * y2 - hz * y1;
        const float t2 = w2v * hx;
        const float c4 = w4v * kInv2;
        const float w3y0 = w3v * y0;
        a0 += m0;
        axx += t2 * y1 + w3y0 * hy + c4 * cx;
        ayy += t2 * y2 + w3y0 * hz + c4 * cy;
        azz += t2 * y3 + w3y0 * hw + c4 * cz;
        hu = hn;
        u0 = n0; u1 = n1; u2 = n2; u3 = n3; u4 = n4;
      }
    }
    const size_t idx = (size_t)n * 64 + lane;
    uint2 t = tq[idx];
    const float tx = blo(t.x) + a0;
    const float ty = bhi(t.x) + axx;
    const float tz = blo(t.y) + ayy;
    const float tw = bhi(t.y) + azz;
    t.x = pk(tx, ty);
    t.y = pk(tz, tw);
    tq[idx] = t;
  }
}

// ---------------------------------------------------------------------------
// K2 (FALLBACK for tiny workspace): R6 fused kernel, bf16 h rows + bf16 tq.
// ---------------------------------------------------------------------------
__global__ __launch_bounds__(512, 4) void k_edge(
    const float* __restrict__ rb, const float* __restrict__ sph,
    const int* __restrict__ ei, const int* __restrict__ eids,
    const int* __restrict__ ends, const int* __restrict__ cnts,
    const float* __restrict__ W1, const float* __restrict__ W2,
    const float* __restrict__ W3, const uint2* __restrict__ hq,
    uint2* __restrict__ tq) {
  extern __shared__ float sm[];
  uint32_t* smu = (uint32_t*)sm;
  for (int i = threadIdx.x; i < 12800; i += 512) {
    if (i < 512) {
      sm[i] = W1[i];
    } else if (i < 2560) {
      const int j = i - 512;
      const int c = j >> 5, kp = j & 31;
      const int dst = 512 + c * 32 + (((kp >> 2) ^ (c & 7)) << 2) + (kp & 3);
      smu[dst] = bf16r(W2[(2 * kp) * 64 + c]) |
                 (bf16r(W2[(2 * kp + 1) * 64 + c]) << 16);
    } else {
      const int j = i - 2560;
      const int q = j >> 11, r = j & 2047;
      const int c = r >> 5, kp = r & 31;
      const int dst =
          2560 + q * 2048 + c * 32 + (((kp >> 2) ^ (c & 7)) << 2) + (kp & 3);
      smu[dst] = bf16r(W3[(2 * kp) * 320 + q * 64 + c]) |
                 (bf16r(W3[(2 * kp + 1) * 320 + q * 64 + c]) << 16);
    }
  }
  __syncthreads();

  const float* sW1 = sm;
  const uint32_t* sW2p = smu + 512;
  const uint32_t* sW3p = smu + 2560;
  const int lane = threadIdx.x & 63;
  const int gw = blockIdx.x * 8 + (threadIdx.x >> 6);
  const int rowoff = lane * 32;
  const int lsw = lane & 7;

  for (int n = gw; n < kN; n += 1024 * 8) {
    int tmp = 0;
    if (lane == 0) tmp = ends[n];
    else if (lane == 1) tmp = cnts[n];
    const int end = bcasti(tmp, 0);
    const int cn = bcasti(tmp, 1);
    float a0 = 0.f, axx = 0.f, ayy = 0.f, azz = 0.f;

    for (int base = end - cn; base < end; base += 64) {
      const int m = min(64, end - base);
      int sidv = 0;
      float4 r0v = make_float4(0.f, 0.f, 0.f, 0.f);
      float4 r1v = r0v, svv = r0v;
      if (lane < m) {
        const int e = eids[base + lane];
        sidv = ei[e];
        r0v = *(const float4*)(rb + (size_t)e * 8);
        r1v = *(const float4*)(rb + (size_t)e * 8 + 4);
        svv = *(const float4*)(sph + (size_t)e * 4);
      }
      const int sid0 = bcasti(sidv, 0);
      uint2 hu = hq[(size_t)sid0 * 64 + lane];

      for (int j = 0; j < m; ++j) {
        uint2 hn = hu;
        if (j + 1 < m) {
          const int sn = bcasti(sidv, j + 1);
          hn = hq[(size_t)sn * 64 + lane];
        }
        const float e0 = bcast(r0v.x, j), e1 = bcast(r0v.y, j);
        const float e2 = bcast(r0v.z, j), e3 = bcast(r0v.w, j);
        const float e4 = bcast(r1v.x, j), e5 = bcast(r1v.y, j);
        const float e6 = bcast(r1v.z, j), e7 = bcast(r1v.w, j);
        const float y0 = bcast(svv.x, j), y1 = bcast(svv.y, j);
        const float y2 = bcast(svv.z, j), y3 = bcast(svv.w, j);

        float acc = e0 * sW1[lane];
        acc = fmaf(e1, sW1[64 + lane], acc);
        acc = fmaf(e2, sW1[128 + lane], acc);
        acc = fmaf(e3, sW1[192 + lane], acc);
        acc = fmaf(e4, sW1[256 + lane], acc);
        acc = fmaf(e5, sW1[320 + lane], acc);
        acc = fmaf(e6, sW1[384 + lane], acc);
        acc = fmaf(e7, sW1[448 + lane], acc);
        const float h1 = silu(acc);

        float acc2 = 0.f;
#pragma unroll
        for (int k8 = 0; k8 < 8; ++k8) {
          const uint4 w = *(const uint4*)(sW2p + rowoff + ((k8 ^ lsw) << 2));
          acc2 = fmaf(bcast(h1, 8 * k8 + 0), blo(w.x), acc2);
          acc2 = fmaf(bcast(h1, 8 * k8 + 1), bhi(w.x), acc2);
          acc2 = fmaf(bcast(h1, 8 * k8 + 2), blo(w.y), acc2);
          acc2 = fmaf(bcast(h1, 8 * k8 + 3), bhi(w.y), acc2);
          acc2 = fmaf(bcast(h1, 8 * k8 + 4), blo(w.z), acc2);
          acc2 = fmaf(bcast(h1, 8 * k8 + 5), bhi(w.z), acc2);
          acc2 = fmaf(bcast(h1, 8 * k8 + 6), blo(w.w), acc2);
          acc2 = fmaf(bcast(h1, 8 * k8 + 7), bhi(w.w), acc2);
        }
        const float h2 = silu(acc2);

        float w0 = 0.f, w1v = 0.f, w2v = 0.f, w3v = 0.f, w4v = 0.f;
#pragma unroll 2
        for (int k8 = 0; k8 < 8; ++k8) {
          const int off = rowoff + ((k8 ^ lsw) << 2);
          const uint4 p0 = *(const uint4*)(sW3p + off);
          const uint4 p1 = *(const uint4*)(sW3p + 2048 + off);
          const uint4 p2 = *(const uint4*)(sW3p + 4096 + off);
          const uint4 p3 = *(const uint4*)(sW3p + 6144 + off);
          const uint4 p4 = *(const uint4*)(sW3p + 8192 + off);
          const float k0 = bcast(h2, 8 * k8 + 0);
          const float k1 = bcast(h2, 8 * k8 + 1);
          const float k2 = bcast(h2, 8 * k8 + 2);
          const float k3 = bcast(h2, 8 * k8 + 3);
          const float k4 = bcast(h2, 8 * k8 + 4);
          const float k5 = bcast(h2, 8 * k8 + 5);
          const float k6 = bcast(h2, 8 * k8 + 6);
          const float k7 = bcast(h2, 8 * k8 + 7);
          w0 = fmaf(k0, blo(p0.x), w0); w0 = fmaf(k1, bhi(p0.x), w0);
          w0 = fmaf(k2, blo(p0.y), w0); w0 = fmaf(k3, bhi(p0.y), w0);
          w0 = fmaf(k4, blo(p0.z), w0); w0 = fmaf(k5, bhi(p0.z), w0);
          w0 = fmaf(k6, blo(p0.w), w0); w0 = fmaf(k7, bhi(p0.w), w0);
          w1v = fmaf(k0, blo(p1.x), w1v); w1v = fmaf(k1, bhi(p1.x), w1v);
          w1v = fmaf(k2, blo(p1.y), w1v); w1v = fmaf(k3, bhi(p1.y), w1v);
          w1v = fmaf(k4, blo(p1.z), w1v); w1v = fmaf(k5, bhi(p1.z), w1v);
          w1v = fmaf(k6, blo(p1.w), w1v); w1v = fmaf(k7, bhi(p1.w), w1v);
          w2v = fmaf(k0, blo(p2.x), w2v); w2v = fmaf(k1, bhi(p2.x), w2v);
          w2v = fmaf(k2, blo(p2.y), w2v); w2v = fmaf(k3, bhi(p2.y), w2v);
          w2v = fmaf(k4, blo(p2.z), w2v); w2v = fmaf(k5, bhi(p2.z), w2v);
          w2v = fmaf(k6, blo(p2.w), w2v); w2v = fmaf(k7, bhi(p2.w), w2v);
          w3v = fmaf(k0, blo(p3.x), w3v); w3v = fmaf(k1, bhi(p3.x), w3v);
          w3v = fmaf(k2, blo(p3.y), w3v); w3v = fmaf(k3, bhi(p3.y), w3v);
          w3v = fmaf(k4, blo(p3.z), w3v); w3v = fmaf(k5, bhi(p3.z), w3v);
          w3v = fmaf(k6, blo(p3.w), w3v); w3v = fmaf(k7, bhi(p3.w), w3v);
          w4v = fmaf(k0, blo(p4.x), w4v); w4v = fmaf(k1, bhi(p4.x), w4v);
          w4v = fmaf(k2, blo(p4.y), w4v); w4v = fmaf(k3, bhi(p4.y), w4v);
          w4v = fmaf(k4, blo(p4.z), w4v); w4v = fmaf(k5, bhi(p4.z), w4v);
          w4v = fmaf(k6, blo(p4.w), w4v); w4v = fmaf(k7, bhi(p4.w), w4v);
        }

        const float hx = blo(hu.x), hy = bhi(hu.x);
        const float hz = blo(hu.y), hw = bhi(hu.y);
        const float dot = hy * y1 + hz * y2 + hw * y3;
        const float m0 = w0 * hx * y0 + w1v * kInv3 * dot;
        const float cx = hz * y3 - hw * y2;
        const float cy = hw * y1 - hy * y3;
        const float cz = hy * y2 - hz * y1;
        const float t2 = w2v * hx;
        const float c4 = w4v * kInv2;
        const float w3y0 = w3v * y0;
        a0 += m0;
        axx += t2 * y1 + w3y0 * hy + c4 * cx;
        ayy += t2 * y2 + w3y0 * hz + c4 * cy;
        azz += t2 * y3 + w3y0 * hw + c4 * cz;
        hu = hn;
      }
    }
    uint2 t;
    t.x = pk(a0, axx);
    t.y = pk(ayy, azz);
    tq[(size_t)n * 64 + lane] = t;
  }
}

// ---------------------------------------------------------------------------
// K3a v5 (MFMA): sc einsum as GEMM (unchanged from R11 — verified working)
// ---------------------------------------------------------------------------
__global__ __launch_bounds__(1024, 2) void k_sc2(
    const float* __restrict__ nf, const float* __restrict__ attrs,
    const unsigned short* __restrict__ xp, const float* __restrict__ scW0,
    const float* __restrict__ scW1, float* __restrict__ scout) {
  extern __shared__ uint32_t sfr[];  // 20480 u32 = 80KB (80 frags)
  const int lane = threadIdx.x & 63, wid = threadIdx.x >> 6;
  const int tile = blockIdx.x * 16 + wid;
  const bool act = (tile < kN / 16);
  const int node = lane & 15, g = lane >> 4;
  const int n = tile * 16 + node;
  const uint4* fr = (const uint4*)sfr;
  const f32x4 z4 = {0.f, 0.f, 0.f, 0.f};

  float at[10];
#pragma unroll
  for (int a = 0; a < 10; ++a)
    at[a] = act ? attrs[(size_t)n * 10 + a] : 0.f;

  // ---- phase 0: W0 frags, x0 (f32 from nf), output plane 0 ----
  for (int i = threadIdx.x; i < 20480; i += 1024) {
    const int f = i >> 8, l = (i >> 2) & 63, jp = i & 3;
    const int kt = f >> 2, mt = f & 3;
    const int c = mt * 16 + (l & 15);
    const int kl = ((l >> 4) << 3) + 2 * jp;
    const int k = ((kt & 1) << 5) + kl, a = kt >> 1;
    sfr[i] = pk(scW0[(size_t)k * 640 + a * 64 + c],
                scW0[(size_t)(k + 1) * 640 + a * 64 + c]);
  }
  __syncthreads();
  if (act) {
    uint32_t x0u[2][4];
#pragma unroll
    for (int kh = 0; kh < 2; ++kh) {
      const float4 v0 = *(const float4*)(nf + (size_t)n * 256 + kh * 32 + g * 8);
      const float4 v1 =
          *(const float4*)(nf + (size_t)n * 256 + kh * 32 + g * 8 + 4);
      x0u[kh][0] = pk(v0.x, v0.y);
      x0u[kh][1] = pk(v0.z, v0.w);
      x0u[kh][2] = pk(v1.x, v1.y);
      x0u[kh][3] = pk(v1.z, v1.w);
    }
    f32x4 acc[4] = {z4, z4, z4, z4};
#pragma unroll 2
    for (int kt = 0; kt < 20; ++kt) {
      const float av = at[kt >> 1];
      const int kh = kt & 1;
      FragU b;
#pragma unroll
      for (int i = 0; i < 4; ++i)
        b.u[i] = pk(av * blo(x0u[kh][i]), av * bhi(x0u[kh][i]));
#pragma unroll
      for (int mt = 0; mt < 4; ++mt) {
        FragU a;
        a.q = fr[(kt * 4 + mt) * 64 + lane];
        acc[mt] = __builtin_amdgcn_mfma_f32_16x16x32_bf16(a.v, b.v, acc[mt],
                                                          0, 0, 0);
      }
    }
#pragma unroll
    for (int mt = 0; mt < 4; ++mt)
#pragma unroll
      for (int r = 0; r < 4; ++r)
        scout[(size_t)n * 64 + mt * 16 + g * 4 + r] = acc[mt][r];
  }
  __syncthreads();

  // ---- phase 1: W1 frags, x1 (bf16 planes), output planes 1..3 ----
  for (int i = threadIdx.x; i < 20480; i += 1024) {
    const int f = i >> 8, l = (i >> 2) & 63, jp = i & 3;
    const int kt = f >> 2, mt = f & 3;
    const int c = mt * 16 + (l & 15);
    const int kl = ((l >> 4) << 3) + 2 * jp;
    const int k = ((kt & 1) << 5) + kl, a = kt >> 1;
    sfr[i] = pk(scW1[(size_t)k * 640 + a * 64 + c],
                scW1[(size_t)(k + 1) * 640 + a * 64 + c]);
  }
  __syncthreads();
  if (act) {
    uint32_t x1u[3][2][4];
#pragma unroll
    for (int m = 0; m < 3; ++m)
#pragma unroll
      for (int kh = 0; kh < 2; ++kh) {
        const uint4 v = *(const uint4*)(xp + (size_t)m * kPl + (size_t)n * 64 +
                                        kh * 32 + g * 8);
        x1u[m][kh][0] = v.x;
        x1u[m][kh][1] = v.y;
        x1u[m][kh][2] = v.z;
        x1u[m][kh][3] = v.w;
      }
    f32x4 acc[3][4] = {{z4, z4, z4, z4}, {z4, z4, z4, z4}, {z4, z4, z4, z4}};
#pragma unroll 2
    for (int kt = 0; kt < 20; ++kt) {
      const float av = at[kt >> 1];
      const int kh = kt & 1;
      FragU b[3];
#pragma unroll
      for (int m = 0; m < 3; ++m)
#pragma unroll
        for (int i = 0; i < 4; ++i)
          b[m].u[i] = pk(av * blo(x1u[m][kh][i]), av * bhi(x1u[m][kh][i]));
#pragma unroll
      for (int mt = 0; mt < 4; ++mt) {
        FragU a;
        a.q = fr[(kt * 4 + mt) * 64 + lane];
#pragma unroll
        for (int m = 0; m < 3; ++m)
          acc[m][mt] = __builtin_amdgcn_mfma_f32_16x16x32_bf16(
              a.v, b[m].v, acc[m][mt], 0, 0, 0);
      }
    }
#pragma unroll
    for (int m = 0; m < 3; ++m)
#pragma unroll
      for (int mt = 0; mt < 4; ++mt)
#pragma unroll
        for (int r = 0; r < 4; ++r)
          scout[(size_t)(m + 1) * kPl + (size_t)n * 64 + mt * 16 + g * 4 + r] =
              acc[m][mt][r];
  }
}

// ---------------------------------------------------------------------------
// K3b: lin transforms, gated nonlinearity, + self-connection (planar scout),
// fin transforms. (R12-measured structure; tcomb now bf16 uint2.)
// ---------------------------------------------------------------------------
__global__ __launch_bounds__(1024, 1) void k_post(
    const float* __restrict__ attrs,
    const float* __restrict__ lin0, const float* __restrict__ lin1,
    const float* __restrict__ c0w, const float* __restrict__ c1w,
    const float* __restrict__ fin0, const float* __restrict__ fin1,
    const uint2* __restrict__ tq, const float* __restrict__ scout,
    float4* __restrict__ out) {
  extern __shared__ float sm[];
  float* sl0 = sm;
  float* sl1 = sm + 4096;
  float* sf0 = sm + 8192;
  float* sf1 = sm + 12288;
  __shared__ float sc0[1920];
  __shared__ float sc1[1280];
  for (int i = threadIdx.x; i < 4096; i += 1024) {
    sl0[i] = lin0[i];
    sl1[i] = lin1[i];
    sf0[i] = fin0[i];
    sf1[i] = fin1[i];
  }
  for (int i = threadIdx.x; i < 1920; i += 1024) sc0[i] = c0w[i];
  for (int i = threadIdx.x; i < 1280; i += 1024) sc1[i] = c1w[i];
  __syncthreads();

  const int lane = threadIdx.x & 63;
  float* sb = sm + 16384 + (threadIdx.x >> 6) * 256;
  for (int n = blockIdx.x * 16 + (threadIdx.x >> 6); n < kN; n += 512 * 16) {
    const uint2 tu = tq[(size_t)n * 64 + lane];
    const float t_x = blo(tu.x), t_y = bhi(tu.x);
    const float t_z = blo(tu.y), t_w = bhi(tu.y);
    float avl = 0.f;
    if (lane < 10) avl = attrs[(size_t)n * 10 + lane];
    float b0 = 0.f, bx = 0.f, by = 0.f, bz = 0.f;
#pragma unroll
    for (int k = 0; k < 64; ++k) {
      const float w0 = sl0[k * 64 + lane];
      const float w1 = sl1[k * 64 + lane];
      b0 = fmaf(bcast(t_x, k), w0, b0);
      bx = fmaf(bcast(t_y, k), w1, bx);
      by = fmaf(bcast(t_z, k), w1, by);
      bz = fmaf(bcast(t_w, k), w1, bz);
    }
    float cw00 = 0.f, cw01 = 0.f, cw02 = 0.f, cw10 = 0.f, cw11 = 0.f;
#pragma unroll
    for (int a = 0; a < 10; ++a) {
      const float av = bcast(avl, a);
      cw00 = fmaf(av, sc0[a * 192 + lane], cw00);
      cw01 = fmaf(av, sc0[a * 192 + 64 + lane], cw01);
      cw02 = fmaf(av, sc0[a * 192 + 128 + lane], cw02);
      cw10 = fmaf(av, sc1[a * 128 + lane], cw10);
      cw11 = fmaf(av, sc1[a * 128 + 64 + lane], cw11);
    }
    const size_t pidx = (size_t)n * 64 + lane;
    const float scx = scout[pidx];
    const float scy = scout[(size_t)kPl + pidx];
    const float scz = scout[(size_t)2 * kPl + pidx];
    const float scw = scout[(size_t)3 * kPl + pidx];
    const float o0 = cw00 * b0 + cw01 * b0 * b0 +
                     cw02 * (bx * bx + by * by + bz * bz) + scx;
    const float o1x = cw10 * bx + cw11 * b0 * bx + scy;
    const float o1y = cw10 * by + cw11 * b0 * by + scz;
    const float o1z = cw10 * bz + cw11 * b0 * bz + scw;
    float f0 = 0.f, fx = 0.f, fy = 0.f, fz = 0.f;
#pragma unroll
    for (int k = 0; k < 64; ++k) {
      const float w0 = sf0[k * 64 + lane];
      const float w1 = sf1[k * 64 + lane];
      f0 = fmaf(bcast(o0, k), w0, f0);
      fx = fmaf(bcast(o1x, k), w1, fx);
      fy = fmaf(bcast(o1y, k), w1, fy);
      fz = fmaf(bcast(o1z, k), w1, fz);
    }
    sb[lane] = f0;
    sb[64 + 3 * lane] = fx;
    sb[64 + 3 * lane + 1] = fy;
    sb[64 + 3 * lane + 2] = fz;
    out[(size_t)n * 64 + lane] = *(const float4*)&sb[lane * 4];
  }
}

}  // namespace

extern "C" void kernel_launch(void* const* d_in, const int* in_sizes, int n_in,
                              void* d_out, int out_size, void* d_ws,
                              size_t ws_size, hipStream_t stream) {
  (void)in_sizes; (void)n_in; (void)out_size;
  const float* nf = (const float*)d_in[0];
  const float* attrs = (const float*)d_in[1];
  const float* sph = (const float*)d_in[2];
  const float* rb = (const float*)d_in[3];
  const int* ei = (const int*)d_in[4];
  const float* preW0 = (const float*)d_in[5];
  const float* preW1 = (const float*)d_in[6];
  const float* mW1 = (const float*)d_in[7];
  const float* mW2 = (const float*)d_in[8];
  const float* mW3 = (const float*)d_in[9];
  const float* lin0 = (const float*)d_in[10];
  const float* lin1 = (const float*)d_in[11];
  const float* c0w = (const float*)d_in[12];
  const float* c1w = (const float*)d_in[13];
  const float* scW0 = (const float*)d_in[14];
  const float* scW1 = (const float*)d_in[15];
  const float* fin0 = (const float*)d_in[16];
  const float* fin1 = (const float*)d_in[17];
  float4* out = (float4*)d_out;

  char* ws = (char*)d_ws;
  uint2* hq = (uint2*)ws;                      // 25.6MB bf16 h (region 51.2MB,
                                               // reused as scout after k_edge2)
  uint2* tq = (uint2*)(ws + 51200000);         // 25.6MB bf16 t (region 51.2MB)
  int* cnts = (int*)(ws + 102400000);          // 200KB
  int* starts = (int*)(ws + 102600000);        // 200KB (ends after scatter)
  int* eids = (int*)(ws + 102800000);          // 3.2MB -> ends 106.0MB
  unsigned short* xp = (unsigned short*)(ws + 106000000);  // 19.2MB bf16 x1
  uint32_t* wbuf = (uint32_t*)(ws + 125200000);
  float* scout = (float*)ws;  // 4 planar f32 planes (51.2MB total)

  // chunk sizing: 640B per slot of bf16 w (uncapped — R11/R14 best config)
  long long avail = (long long)ws_size - 125200000ll;
  long long cs64 = (avail > 0) ? avail / 640 : 0;
  if (cs64 > kE) cs64 = kE;
  const int chunkSlots = (int)(cs64 & ~15ll);
  const bool mfma = (chunkSlots >= 64000);

  hipMemsetAsync(cnts, 0, kN * sizeof(int), stream);
  k_pre<<<2048, 256, 0, stream>>>(nf, preW0, preW1, hq, xp);
  k_hist<<<(kE + 255) / 256, 256, 0, stream>>>(ei, cnts);
  k_scan<<<1, 1024, 0, stream>>>(cnts, starts);
  k_scatter<<<(kE + 255) / 256, 256, 0, stream>>>(ei, starts, eids);

  if (mfma) {
    hipMemsetAsync(tq, 0, (size_t)kN * 512, stream);
    int done = 0;
    while (done < kE) {
      const int cs = (kE - done < chunkSlots) ? (kE - done) : chunkSlots;
      const int tiles = cs / 16;
      k_mlp<<<1536, 256, 0, stream>>>(rb, eids, mW1, mW2, mW3, wbuf,
                                      done / 16, tiles);
      k_edge2<<<1024, 1024, 0, stream>>>(sph, ei, eids, starts, cnts, wbuf,
                                         hq, tq, done, done + cs);
      done += cs;
    }
  } else {
    hipFuncSetAttribute((const void*)k_edge,
                        hipFuncAttributeMaxDynamicSharedMemorySize, 12800 * 4);
    k_edge<<<1024, 512, 12800 * 4, stream>>>(rb, sph, ei, eids, starts, cnts,
                                             mW1, mW2, mW3, hq, tq);
  }

  hipFuncSetAttribute((const void*)k_sc2,
                      hipFuncAttributeMaxDynamicSharedMemorySize, 81920);
  k_sc2<<<196, 1024, 81920, stream>>>(nf, attrs, xp, scW0, scW1, scout);

  hipFuncSetAttribute((const void*)k_post,
                      hipFuncAttributeMaxDynamicSharedMemorySize, 20480 * 4);
  k_post<<<512, 1024, 20480 * 4, stream>>>(attrs, lin0, lin1, c0w, c1w,
                                           fin0, fin1, tq, scout, out);
}

// Round 18
// 1075.889 us; speedup vs baseline: 1.0491x; 1.0491x over previous
//
#include <hip/hip_runtime.h>
#include <hip/hip_bf16.h>
#include <cstdint>
#include <cstddef>

namespace {

constexpr int kN = 50000;   // nodes
constexpr int kE = 800000;  // edges
constexpr int kPl = 3200000;  // plane elements (kN*64)
constexpr float kInv3 = 0.57735026918962576451f; // 1/sqrt(3)
constexpr float kInv2 = 0.70710678118654752440f; // 1/sqrt(2)

typedef __attribute__((ext_vector_type(8))) short bf16x8;
typedef __attribute__((ext_vector_type(4))) float f32x4;
union FragU { uint32_t u[4]; bf16x8 v; uint4 q; };

__device__ __forceinline__ float bcast(float v, int k) {
  return __int_as_float(__builtin_amdgcn_readlane(__float_as_int(v), k));
}
__device__ __forceinline__ int bcasti(int v, int k) {
  return __builtin_amdgcn_readlane(v, k);
}
__device__ __forceinline__ float silu(float x) {
  return x / (1.0f + __expf(-x));
}
__device__ __forceinline__ uint32_t bf16r(float f) {  // RTNE
  uint32_t u = __float_as_uint(f);
  return (u + 0x7fffu + ((u >> 16) & 1u)) >> 16;
}
__device__ __forceinline__ float blo(uint32_t u) { return __uint_as_float(u << 16); }
__device__ __forceinline__ float bhi(uint32_t u) { return __uint_as_float(u & 0xffff0000u); }
__device__ __forceinline__ uint32_t pk(float a, float b) {
  union { __hip_bfloat16 h; unsigned short s; } x, y;
  x.h = __float2bfloat16(a);
  y.h = __float2bfloat16(b);
  return (uint32_t)x.s | ((uint32_t)y.s << 16);
}

// ---------------------------------------------------------------------------
// K1: h0 = x0 @ pre_W0 ; h1[:,:,m] = x1[:,:,m] @ pre_W1
// h output packed bf16x4 (uint2/lane). Also emits planar bf16 x1 (xp).
// ---------------------------------------------------------------------------
__global__ __launch_bounds__(256) void k_pre(const float* __restrict__ nf,
                                             const float* __restrict__ W0,
                                             const float* __restrict__ W1,
                                             uint2* __restrict__ hq,
                                             unsigned short* __restrict__ xp) {
  __shared__ float sW[8192];
  __shared__ float sbuf[4][256];
  for (int i = threadIdx.x; i < 8192; i += 256)
    sW[i] = (i < 4096) ? W0[i] : W1[i - 4096];
  __syncthreads();

  const int wid = threadIdx.x >> 6, lane = threadIdx.x & 63;
  for (int nb = blockIdx.x * 4; nb < kN; nb += 2048 * 4) {
    const int n = nb + wid;
    if (n >= kN) continue;
    const float4 rv = ((const float4*)nf)[(size_t)n * 64 + lane];
    *(float4*)&sbuf[wid][lane * 4] = rv;
    const float v0 = sbuf[wid][lane];
    const float vx = sbuf[wid][64 + 3 * lane];
    const float vy = sbuf[wid][64 + 3 * lane + 1];
    const float vz = sbuf[wid][64 + 3 * lane + 2];
    xp[(size_t)n * 64 + lane] = (unsigned short)bf16r(vx);
    xp[(size_t)kPl + (size_t)n * 64 + lane] = (unsigned short)bf16r(vy);
    xp[(size_t)2 * kPl + (size_t)n * 64 + lane] = (unsigned short)bf16r(vz);
    float a0 = 0.f, ax = 0.f, ay = 0.f, az = 0.f;
#pragma unroll
    for (int k = 0; k < 64; ++k) {
      const float w0 = sW[k * 64 + lane];
      const float w1 = sW[4096 + k * 64 + lane];
      a0 = fmaf(bcast(v0, k), w0, a0);
      ax = fmaf(bcast(vx, k), w1, ax);
      ay = fmaf(bcast(vy, k), w1, ay);
      az = fmaf(bcast(vz, k), w1, az);
    }
    uint2 hv;
    hv.x = pk(a0, ax);
    hv.y = pk(ay, az);
    hq[(size_t)n * 64 + lane] = hv;
  }
}

// ---------------------------------------------------------------------------
// CSR build
// ---------------------------------------------------------------------------
__global__ void k_hist(const int* __restrict__ ei, int* __restrict__ cnt) {
  const int e = blockIdx.x * blockDim.x + threadIdx.x;
  if (e < kE) atomicAdd(&cnt[ei[kE + e]], 1);
}

__global__ __launch_bounds__(1024) void k_scan(const int* __restrict__ cnt,
                                               int* __restrict__ starts) {
  __shared__ int sh[1024];
  const int t = threadIdx.x;
  constexpr int CH = 49;
  const int base = t * CH;
  int s = 0;
  for (int i = 0; i < CH; ++i) {
    const int idx = base + i;
    if (idx < kN) s += cnt[idx];
  }
  sh[t] = s;
  __syncthreads();
  for (int off = 1; off < 1024; off <<= 1) {
    const int v = sh[t];
    const int o = (t >= off) ? sh[t - off] : 0;
    __syncthreads();
    sh[t] = v + o;
    __syncthreads();
  }
  int run = sh[t] - s;
  for (int i = 0; i < CH; ++i) {
    const int idx = base + i;
    if (idx < kN) {
      starts[idx] = run;
      run += cnt[idx];
    }
  }
}

__global__ void k_scatter(const int* __restrict__ ei, int* __restrict__ cursor,
                          int* __restrict__ eids) {
  const int e = blockIdx.x * blockDim.x + threadIdx.x;
  if (e < kE) {
    const int pos = atomicAdd(&cursor[ei[kE + e]], 1);
    eids[pos] = e;
  }
}

// ---------------------------------------------------------------------------
// K2a (MFMA): per-wave 16-edge tile runs the radial MLP as 3 chained GEMMs.
// (R8-verified; grid 768 — R17's 1536 doubled the 52KB staging cost, -38us)
// ---------------------------------------------------------------------------
__device__ __forceinline__ void xpose(const uint32_t* pa, const uint32_t* pb,
                                      int addr0, int addr1, bool ghi,
                                      FragU* out) {
#pragma unroll
  for (int kt = 0; kt < 2; ++kt) {
    const int m0 = 2 * kt, m1 = 2 * kt + 1;
    int t0, t1;
    t0 = __builtin_amdgcn_ds_bpermute(addr0, (int)pa[m0]);
    t1 = __builtin_amdgcn_ds_bpermute(addr0, (int)pa[m1]);
    out[kt].u[0] = (uint32_t)(ghi ? t1 : t0);
    t0 = __builtin_amdgcn_ds_bpermute(addr0, (int)pb[m0]);
    t1 = __builtin_amdgcn_ds_bpermute(addr0, (int)pb[m1]);
    out[kt].u[1] = (uint32_t)(ghi ? t1 : t0);
    t0 = __builtin_amdgcn_ds_bpermute(addr1, (int)pa[m0]);
    t1 = __builtin_amdgcn_ds_bpermute(addr1, (int)pa[m1]);
    out[kt].u[2] = (uint32_t)(ghi ? t1 : t0);
    t0 = __builtin_amdgcn_ds_bpermute(addr1, (int)pb[m0]);
    t1 = __builtin_amdgcn_ds_bpermute(addr1, (int)pb[m1]);
    out[kt].u[3] = (uint32_t)(ghi ? t1 : t0);
  }
}

__global__ __launch_bounds__(256, 2) void k_mlp(
    const float* __restrict__ rb, const int* __restrict__ eids,
    const float* __restrict__ W1f, const float* __restrict__ W2f,
    const float* __restrict__ W3f, uint32_t* __restrict__ wout,
    int tile0, int ntiles) {
  __shared__ uint32_t sfrag[13312];  // 52 frags x 256 u32
  for (int i = threadIdx.x; i < 13312; i += 256) {
    const int f = i >> 8, l = (i >> 2) & 63, jp = i & 3;
    const int kk = ((l >> 4) << 3) + 2 * jp;
    float a, b;
    if (f < 4) {  // W1^T, K padded 8->32 with zeros
      const int c = (f << 4) + (l & 15);
      a = (kk < 8) ? W1f[kk * 64 + c] : 0.f;
      b = (kk < 7) ? W1f[(kk + 1) * 64 + c] : 0.f;
    } else if (f < 12) {  // W2^T: frag (kt, mt)
      const int kt = (f - 4) >> 2, mt = (f - 4) & 3;
      const int k = kt * 32 + kk, c = (mt << 4) + (l & 15);
      a = W2f[k * 64 + c];
      b = W2f[(k + 1) * 64 + c];
    } else {  // W3^T: frag (kt, mt), mt 0..19
      const int kt = (f - 12) / 20, mt = (f - 12) % 20;
      const int k = kt * 32 + kk, c = (mt << 4) + (l & 15);
      a = W3f[k * 320 + c];
      b = W3f[(k + 1) * 320 + c];
    }
    sfrag[i] = pk(a, b);
  }
  __syncthreads();

  const int lane = threadIdx.x & 63;
  const int e15 = lane & 15, g = lane >> 4;
  const uint4* fr = (const uint4*)sfrag;
  const int wv = blockIdx.x * 4 + (threadIdx.x >> 6);
  const int addr0 = ((((g & 1) << 1)) * 16 + e15) * 4;
  const int addr1 = addr0 + 64;
  const bool ghi = (g >> 1) != 0;
  const f32x4 z = {0.f, 0.f, 0.f, 0.f};

  for (int t = wv; t < ntiles; t += 768 * 4) {
    FragU b1;
    b1.u[0] = b1.u[1] = b1.u[2] = b1.u[3] = 0;
    if (lane < 16) {
      const int e = eids[(size_t)(tile0 + t) * 16 + lane];
      const float4 r0 = *(const float4*)(rb + (size_t)e * 8);
      const float4 r1 = *(const float4*)(rb + (size_t)e * 8 + 4);
      b1.u[0] = pk(r0.x, r0.y);
      b1.u[1] = pk(r0.z, r0.w);
      b1.u[2] = pk(r1.x, r1.y);
      b1.u[3] = pk(r1.z, r1.w);
    }

    uint32_t pa[4], pb[4];
#pragma unroll
    for (int mt = 0; mt < 4; ++mt) {
      FragU a;
      a.q = fr[(mt << 6) + lane];
      f32x4 d = __builtin_amdgcn_mfma_f32_16x16x32_bf16(a.v, b1.v, z, 0, 0, 0);
      pa[mt] = pk(silu(d[0]), silu(d[1]));
      pb[mt] = pk(silu(d[2]), silu(d[3]));
    }
    FragU b2[2];
    xpose(pa, pb, addr0, addr1, ghi, b2);

    f32x4 d2[4] = {z, z, z, z};
#pragma unroll
    for (int kt = 0; kt < 2; ++kt)
#pragma unroll
      for (int mt = 0; mt < 4; ++mt) {
        FragU a;
        a.q = fr[((4 + kt * 4 + mt) << 6) + lane];
        d2[mt] =
            __builtin_amdgcn_mfma_f32_16x16x32_bf16(a.v, b2[kt].v, d2[mt], 0, 0, 0);
      }
#pragma unroll
    for (int mt = 0; mt < 4; ++mt) {
      pa[mt] = pk(silu(d2[mt][0]), silu(d2[mt][1]));
      pb[mt] = pk(silu(d2[mt][2]), silu(d2[mt][3]));
    }
    FragU b3[2];
    xpose(pa, pb, addr0, addr1, ghi, b3);

    uint32_t* wt = wout + (size_t)t * 2560 + lane;
#pragma unroll 4
    for (int mt = 0; mt < 20; ++mt) {
      FragU a0, a1;
      a0.q = fr[((12 + mt) << 6) + lane];
      a1.q = fr[((32 + mt) << 6) + lane];
      f32x4 d = __builtin_amdgcn_mfma_f32_16x16x32_bf16(a0.v, b3[0].v, z, 0, 0, 0);
      d = __builtin_amdgcn_mfma_f32_16x16x32_bf16(a1.v, b3[1].v, d, 0, 0, 0);
      wt[mt * 128] = pk(d[0], d[1]);
      wt[mt * 128 + 64] = pk(d[2], d[3]);
    }
  }
}

// ---------------------------------------------------------------------------
// K2b: slim consumer over slot range [lo, hi). bf16 h rows; tcomb bf16x4
// (uint2) RMW. Grid 512 (R17's 1024 doubled header rescans).
// ---------------------------------------------------------------------------
__global__ __launch_bounds__(1024, 6) void k_edge2(
    const float* __restrict__ sph, const int* __restrict__ ei,
    const int* __restrict__ eids, const int* __restrict__ ends,
    const int* __restrict__ cnts, const uint32_t* __restrict__ w32,
    const uint2* __restrict__ hq, uint2* __restrict__ tq,
    int lo, int hi) {
  const int lane = threadIdx.x & 63;
  const int LCb = ((lane >> 4) << 7) + (((lane & 3) >> 1) << 6) +
                  (((lane >> 2) & 3) << 4);
  const uint32_t shl = (lane & 1) ? 0u : 16u;
  const int gw = blockIdx.x * 16 + (threadIdx.x >> 6);
  for (int n = gw; n < kN; n += 512 * 16) {
    int tmp = 0;
    if (lane == 0) tmp = ends[n];
    else if (lane == 1) tmp = cnts[n];
    const int end = bcasti(tmp, 0);
    const int cn = bcasti(tmp, 1);
    const int s0 = max(end - cn, lo);
    const int s1 = min(end, hi);
    if (s0 >= s1) continue;
    float a0 = 0.f, axx = 0.f, ayy = 0.f, azz = 0.f;

    for (int base = s0; base < s1; base += 64) {
      const int m = min(64, s1 - base);
      int sidv = 0;
      float4 svv = make_float4(0.f, 0.f, 0.f, 0.f);
      if (lane < m) {
        const int ev = eids[base + lane];
        sidv = ei[ev];
        svv = *(const float4*)(sph + (size_t)ev * 4);
      }
      // preload edge 0
      const int scur = bcasti(sidv, 0);
      uint2 hu = hq[(size_t)scur * 64 + lane];
      const int sl0 = base - lo;
      size_t wi = (size_t)(sl0 >> 4) * 2560 + (sl0 & 15) + LCb;
      uint32_t u0 = w32[wi], u1 = w32[wi + 512], u2 = w32[wi + 1024],
               u3 = w32[wi + 1536], u4 = w32[wi + 2048];

      for (int j = 0; j < m; ++j) {
        uint2 hn = hu;
        uint32_t n0 = u0, n1 = u1, n2 = u2, n3 = u3, n4 = u4;
        if (j + 1 < m) {
          const int sn = bcasti(sidv, j + 1);
          hn = hq[(size_t)sn * 64 + lane];
          const int sl = base + j + 1 - lo;
          const size_t wj = (size_t)(sl >> 4) * 2560 + (sl & 15) + LCb;
          n0 = w32[wj];
          n1 = w32[wj + 512];
          n2 = w32[wj + 1024];
          n3 = w32[wj + 1536];
          n4 = w32[wj + 2048];
        }
        const float y0 = bcast(svv.x, j), y1 = bcast(svv.y, j);
        const float y2 = bcast(svv.z, j), y3 = bcast(svv.w, j);
        const float hx = blo(hu.x), hy = bhi(hu.x);
        const float hz = blo(hu.y), hw = bhi(hu.y);
        const float w0 = __uint_as_float((u0 << shl) & 0xffff0000u);
        const float w1v = __uint_as_float((u1 << shl) & 0xffff0000u);
        const float w2v = __uint_as_float((u2 << shl) & 0xffff0000u);
        const float w3v = __uint_as_float((u3 << shl) & 0xffff0000u);
        const float w4v = __uint_as_float((u4 << shl) & 0xffff0000u);

        const float dot = hy * y1 + hz * y2 + hw * y3;
        const float m0 = w0 * hx * y0 + w1v * kInv3 * dot;
        const float cx = hz * y3 - hw * y2;
        const float cy = hw * y1 - hy * y3;
        const float cz = hy * y2 - hz * y1;
        const float t2 = w2v * hx;
        const float c4 = w4v * kInv2;
        const float w3y0 = w3v * y0;
        a0 += m0;
        axx += t2 * y1 + w3y0 * hy + c4 * cx;
        ayy += t2 * y2 + w3y0 * hz + c4 * cy;
        azz += t2 * y3 + w3y0 * hw + c4 * cz;
        hu = hn;
        u0 = n0; u1 = n1; u2 = n2; u3 = n3; u4 = n4;
      }
    }
    const size_t idx = (size_t)n * 64 + lane;
    uint2 t = tq[idx];
    const float tx = blo(t.x) + a0;
    const float ty = bhi(t.x) + axx;
    const float tz = blo(t.y) + ayy;
    const float tw = bhi(t.y) + azz;
    t.x = pk(tx, ty);
    t.y = pk(tz, tw);
    tq[idx] = t;
  }
}

// ---------------------------------------------------------------------------
// K2 (FALLBACK for tiny workspace): R6 fused kernel, bf16 h rows + bf16 tq.
// ---------------------------------------------------------------------------
__global__ __launch_bounds__(512, 4) void k_edge(
    const float* __restrict__ rb, const float* __restrict__ sph,
    const int* __restrict__ ei, const int* __restrict__ eids,
    const int* __restrict__ ends, const int* __restrict__ cnts,
    const float* __restrict__ W1, const float* __restrict__ W2,
    const float* __restrict__ W3, const uint2* __restrict__ hq,
    uint2* __restrict__ tq) {
  extern __shared__ float sm[];
  uint32_t* smu = (uint32_t*)sm;
  for (int i = threadIdx.x; i < 12800; i += 512) {
    if (i < 512) {
      sm[i] = W1[i];
    } else if (i < 2560) {
      const int j = i - 512;
      const int c = j >> 5, kp = j & 31;
      const int dst = 512 + c * 32 + (((kp >> 2) ^ (c & 7)) << 2) + (kp & 3);
      smu[dst] = bf16r(W2[(2 * kp) * 64 + c]) |
                 (bf16r(W2[(2 * kp + 1) * 64 + c]) << 16);
    } else {
      const int j = i - 2560;
      const int q = j >> 11, r = j & 2047;
      const int c = r >> 5, kp = r & 31;
      const int dst =
          2560 + q * 2048 + c * 32 + (((kp >> 2) ^ (c & 7)) << 2) + (kp & 3);
      smu[dst] = bf16r(W3[(2 * kp) * 320 + q * 64 + c]) |
                 (bf16r(W3[(2 * kp + 1) * 320 + q * 64 + c]) << 16);
    }
  }
  __syncthreads();

  const float* sW1 = sm;
  const uint32_t* sW2p = smu + 512;
  const uint32_t* sW3p = smu + 2560;
  const int lane = threadIdx.x & 63;
  const int gw = blockIdx.x * 8 + (threadIdx.x >> 6);
  const int rowoff = lane * 32;
  const int lsw = lane & 7;

  for (int n = gw; n < kN; n += 1024 * 8) {
    int tmp = 0;
    if (lane == 0) tmp = ends[n];
    else if (lane == 1) tmp = cnts[n];
    const int end = bcasti(tmp, 0);
    const int cn = bcasti(tmp, 1);
    float a0 = 0.f, axx = 0.f, ayy = 0.f, azz = 0.f;

    for (int base = end - cn; base < end; base += 64) {
      const int m = min(64, end - base);
      int sidv = 0;
      float4 r0v = make_float4(0.f, 0.f, 0.f, 0.f);
      float4 r1v = r0v, svv = r0v;
      if (lane < m) {
        const int e = eids[base + lane];
        sidv = ei[e];
        r0v = *(const float4*)(rb + (size_t)e * 8);
        r1v = *(const float4*)(rb + (size_t)e * 8 + 4);
        svv = *(const float4*)(sph + (size_t)e * 4);
      }
      const int sid0 = bcasti(sidv, 0);
      uint2 hu = hq[(size_t)sid0 * 64 + lane];

      for (int j = 0; j < m; ++j) {
        uint2 hn = hu;
        if (j + 1 < m) {
          const int sn = bcasti(sidv, j + 1);
          hn = hq[(size_t)sn * 64 + lane];
        }
        const float e0 = bcast(r0v.x, j), e1 = bcast(r0v.y, j);
        const float e2 = bcast(r0v.z, j), e3 = bcast(r0v.w, j);
        const float e4 = bcast(r1v.x, j), e5 = bcast(r1v.y, j);
        const float e6 = bcast(r1v.z, j), e7 = bcast(r1v.w, j);
        const float y0 = bcast(svv.x, j), y1 = bcast(svv.y, j);
        const float y2 = bcast(svv.z, j), y3 = bcast(svv.w, j);

        float acc = e0 * sW1[lane];
        acc = fmaf(e1, sW1[64 + lane], acc);
        acc = fmaf(e2, sW1[128 + lane], acc);
        acc = fmaf(e3, sW1[192 + lane], acc);
        acc = fmaf(e4, sW1[256 + lane], acc);
        acc = fmaf(e5, sW1[320 + lane], acc);
        acc = fmaf(e6, sW1[384 + lane], acc);
        acc = fmaf(e7, sW1[448 + lane], acc);
        const float h1 = silu(acc);

        float acc2 = 0.f;
#pragma unroll
        for (int k8 = 0; k8 < 8; ++k8) {
          const uint4 w = *(const uint4*)(sW2p + rowoff + ((k8 ^ lsw) << 2));
          acc2 = fmaf(bcast(h1, 8 * k8 + 0), blo(w.x), acc2);
          acc2 = fmaf(bcast(h1, 8 * k8 + 1), bhi(w.x), acc2);
          acc2 = fmaf(bcast(h1, 8 * k8 + 2), blo(w.y), acc2);
          acc2 = fmaf(bcast(h1, 8 * k8 + 3), bhi(w.y), acc2);
          acc2 = fmaf(bcast(h1, 8 * k8 + 4), blo(w.z), acc2);
          acc2 = fmaf(bcast(h1, 8 * k8 + 5), bhi(w.z), acc2);
          acc2 = fmaf(bcast(h1, 8 * k8 + 6), blo(w.w), acc2);
          acc2 = fmaf(bcast(h1, 8 * k8 + 7), bhi(w.w), acc2);
        }
        const float h2 = silu(acc2);

        float w0 = 0.f, w1v = 0.f, w2v = 0.f, w3v = 0.f, w4v = 0.f;
#pragma unroll 2
        for (int k8 = 0; k8 < 8; ++k8) {
          const int off = rowoff + ((k8 ^ lsw) << 2);
          const uint4 p0 = *(const uint4*)(sW3p + off);
          const uint4 p1 = *(const uint4*)(sW3p + 2048 + off);
          const uint4 p2 = *(const uint4*)(sW3p + 4096 + off);
          const uint4 p3 = *(const uint4*)(sW3p + 6144 + off);
          const uint4 p4 = *(const uint4*)(sW3p + 8192 + off);
          const float k0 = bcast(h2, 8 * k8 + 0);
          const float k1 = bcast(h2, 8 * k8 + 1);
          const float k2 = bcast(h2, 8 * k8 + 2);
          const float k3 = bcast(h2, 8 * k8 + 3);
          const float k4 = bcast(h2, 8 * k8 + 4);
          const float k5 = bcast(h2, 8 * k8 + 5);
          const float k6 = bcast(h2, 8 * k8 + 6);
          const float k7 = bcast(h2, 8 * k8 + 7);
          w0 = fmaf(k0, blo(p0.x), w0); w0 = fmaf(k1, bhi(p0.x), w0);
          w0 = fmaf(k2, blo(p0.y), w0); w0 = fmaf(k3, bhi(p0.y), w0);
          w0 = fmaf(k4, blo(p0.z), w0); w0 = fmaf(k5, bhi(p0.z), w0);
          w0 = fmaf(k6, blo(p0.w), w0); w0 = fmaf(k7, bhi(p0.w), w0);
          w1v = fmaf(k0, blo(p1.x), w1v); w1v = fmaf(k1, bhi(p1.x), w1v);
          w1v = fmaf(k2, blo(p1.y), w1v); w1v = fmaf(k3, bhi(p1.y), w1v);
          w1v = fmaf(k4, blo(p1.z), w1v); w1v = fmaf(k5, bhi(p1.z), w1v);
          w1v = fmaf(k6, blo(p1.w), w1v); w1v = fmaf(k7, bhi(p1.w), w1v);
          w2v = fmaf(k0, blo(p2.x), w2v); w2v = fmaf(k1, bhi(p2.x), w2v);
          w2v = fmaf(k2, blo(p2.y), w2v); w2v = fmaf(k3, bhi(p2.y), w2v);
          w2v = fmaf(k4, blo(p2.z), w2v); w2v = fmaf(k5, bhi(p2.z), w2v);
          w2v = fmaf(k6, blo(p2.w), w2v); w2v = fmaf(k7, bhi(p2.w), w2v);
          w3v = fmaf(k0, blo(p3.x), w3v); w3v = fmaf(k1, bhi(p3.x), w3v);
          w3v = fmaf(k2, blo(p3.y), w3v); w3v = fmaf(k3, bhi(p3.y), w3v);
          w3v = fmaf(k4, blo(p3.z), w3v); w3v = fmaf(k5, bhi(p3.z), w3v);
          w3v = fmaf(k6, blo(p3.w), w3v); w3v = fmaf(k7, bhi(p3.w), w3v);
          w4v = fmaf(k0, blo(p4.x), w4v); w4v = fmaf(k1, bhi(p4.x), w4v);
          w4v = fmaf(k2, blo(p4.y), w4v); w4v = fmaf(k3, bhi(p4.y), w4v);
          w4v = fmaf(k4, blo(p4.z), w4v); w4v = fmaf(k5, bhi(p4.z), w4v);
          w4v = fmaf(k6, blo(p4.w), w4v); w4v = fmaf(k7, bhi(p4.w), w4v);
        }

        const float hx = blo(hu.x), hy = bhi(hu.x);
        const float hz = blo(hu.y), hw = bhi(hu.y);
        const float dot = hy * y1 + hz * y2 + hw * y3;
        const float m0 = w0 * hx * y0 + w1v * kInv3 * dot;
        const float cx = hz * y3 - hw * y2;
        const float cy = hw * y1 - hy * y3;
        const float cz = hy * y2 - hz * y1;
        const float t2 = w2v * hx;
        const float c4 = w4v * kInv2;
        const float w3y0 = w3v * y0;
        a0 += m0;
        axx += t2 * y1 + w3y0 * hy + c4 * cx;
        ayy += t2 * y2 + w3y0 * hz + c4 * cy;
        azz += t2 * y3 + w3y0 * hw + c4 * cz;
        hu = hn;
      }
    }
    uint2 t;
    t.x = pk(a0, axx);
    t.y = pk(ayy, azz);
    tq[(size_t)n * 64 + lane] = t;
  }
}

// ---------------------------------------------------------------------------
// K3a v5 (MFMA): sc einsum as GEMM (unchanged from R11 — verified working)
// ---------------------------------------------------------------------------
__global__ __launch_bounds__(1024, 2) void k_sc2(
    const float* __restrict__ nf, const float* __restrict__ attrs,
    const unsigned short* __restrict__ xp, const float* __restrict__ scW0,
    const float* __restrict__ scW1, float* __restrict__ scout) {
  extern __shared__ uint32_t sfr[];  // 20480 u32 = 80KB (80 frags)
  const int lane = threadIdx.x & 63, wid = threadIdx.x >> 6;
  const int tile = blockIdx.x * 16 + wid;
  const bool act = (tile < kN / 16);
  const int node = lane & 15, g = lane >> 4;
  const int n = tile * 16 + node;
  const uint4* fr = (const uint4*)sfr;
  const f32x4 z4 = {0.f, 0.f, 0.f, 0.f};

  float at[10];
#pragma unroll
  for (int a = 0; a < 10; ++a)
    at[a] = act ? attrs[(size_t)n * 10 + a] : 0.f;

  // ---- phase 0: W0 frags, x0 (f32 from nf), output plane 0 ----
  for (int i = threadIdx.x; i < 20480; i += 1024) {
    const int f = i >> 8, l = (i >> 2) & 63, jp = i & 3;
    const int kt = f >> 2, mt = f & 3;
    const int c = mt * 16 + (l & 15);
    const int kl = ((l >> 4) << 3) + 2 * jp;
    const int k = ((kt & 1) << 5) + kl, a = kt >> 1;
    sfr[i] = pk(scW0[(size_t)k * 640 + a * 64 + c],
                scW0[(size_t)(k + 1) * 640 + a * 64 + c]);
  }
  __syncthreads();
  if (act) {
    uint32_t x0u[2][4];
#pragma unroll
    for (int kh = 0; kh < 2; ++kh) {
      const float4 v0 = *(const float4*)(nf + (size_t)n * 256 + kh * 32 + g * 8);
      const float4 v1 =
          *(const float4*)(nf + (size_t)n * 256 + kh * 32 + g * 8 + 4);
      x0u[kh][0] = pk(v0.x, v0.y);
      x0u[kh][1] = pk(v0.z, v0.w);
      x0u[kh][2] = pk(v1.x, v1.y);
      x0u[kh][3] = pk(v1.z, v1.w);
    }
    f32x4 acc[4] = {z4, z4, z4, z4};
#pragma unroll 2
    for (int kt = 0; kt < 20; ++kt) {
      const float av = at[kt >> 1];
      const int kh = kt & 1;
      FragU b;
#pragma unroll
      for (int i = 0; i < 4; ++i)
        b.u[i] = pk(av * blo(x0u[kh][i]), av * bhi(x0u[kh][i]));
#pragma unroll
      for (int mt = 0; mt < 4; ++mt) {
        FragU a;
        a.q = fr[(kt * 4 + mt) * 64 + lane];
        acc[mt] = __builtin_amdgcn_mfma_f32_16x16x32_bf16(a.v, b.v, acc[mt],
                                                          0, 0, 0);
      }
    }
#pragma unroll
    for (int mt = 0; mt < 4; ++mt)
#pragma unroll
      for (int r = 0; r < 4; ++r)
        scout[(size_t)n * 64 + mt * 16 + g * 4 + r] = acc[mt][r];
  }
  __syncthreads();

  // ---- phase 1: W1 frags, x1 (bf16 planes), output planes 1..3 ----
  for (int i = threadIdx.x; i < 20480; i += 1024) {
    const int f = i >> 8, l = (i >> 2) & 63, jp = i & 3;
    const int kt = f >> 2, mt = f & 3;
    const int c = mt * 16 + (l & 15);
    const int kl = ((l >> 4) << 3) + 2 * jp;
    const int k = ((kt & 1) << 5) + kl, a = kt >> 1;
    sfr[i] = pk(scW1[(size_t)k * 640 + a * 64 + c],
                scW1[(size_t)(k + 1) * 640 + a * 64 + c]);
  }
  __syncthreads();
  if (act) {
    uint32_t x1u[3][2][4];
#pragma unroll
    for (int m = 0; m < 3; ++m)
#pragma unroll
      for (int kh = 0; kh < 2; ++kh) {
        const uint4 v = *(const uint4*)(xp + (size_t)m * kPl + (size_t)n * 64 +
                                        kh * 32 + g * 8);
        x1u[m][kh][0] = v.x;
        x1u[m][kh][1] = v.y;
        x1u[m][kh][2] = v.z;
        x1u[m][kh][3] = v.w;
      }
    f32x4 acc[3][4] = {{z4, z4, z4, z4}, {z4, z4, z4, z4}, {z4, z4, z4, z4}};
#pragma unroll 2
    for (int kt = 0; kt < 20; ++kt) {
      const float av = at[kt >> 1];
      const int kh = kt & 1;
      FragU b[3];
#pragma unroll
      for (int m = 0; m < 3; ++m)
#pragma unroll
        for (int i = 0; i < 4; ++i)
          b[m].u[i] = pk(av * blo(x1u[m][kh][i]), av * bhi(x1u[m][kh][i]));
#pragma unroll
      for (int mt = 0; mt < 4; ++mt) {
        FragU a;
        a.q = fr[(kt * 4 + mt) * 64 + lane];
#pragma unroll
        for (int m = 0; m < 3; ++m)
          acc[m][mt] = __builtin_amdgcn_mfma_f32_16x16x32_bf16(
              a.v, b[m].v, acc[m][mt], 0, 0, 0);
      }
    }
#pragma unroll
    for (int m = 0; m < 3; ++m)
#pragma unroll
      for (int mt = 0; mt < 4; ++mt)
#pragma unroll
        for (int r = 0; r < 4; ++r)
          scout[(size_t)(m + 1) * kPl + (size_t)n * 64 + mt * 16 + g * 4 + r] =
              acc[m][mt][r];
  }
}

// ---------------------------------------------------------------------------
// K3b: lin transforms, gated nonlinearity, + self-connection (planar scout),
// fin transforms. (R12-measured structure; tcomb bf16 uint2.)
// ---------------------------------------------------------------------------
__global__ __launch_bounds__(1024, 1) void k_post(
    const float* __restrict__ attrs,
    const float* __restrict__ lin0, const float* __restrict__ lin1,
    const float* __restrict__ c0w, const float* __restrict__ c1w,
    const float* __restrict__ fin0, const float* __restrict__ fin1,
    const uint2* __restrict__ tq, const float* __restrict__ scout,
    float4* __restrict__ out) {
  extern __shared__ float sm[];
  float* sl0 = sm;
  float* sl1 = sm + 4096;
  float* sf0 = sm + 8192;
  float* sf1 = sm + 12288;
  __shared__ float sc0[1920];
  __shared__ float sc1[1280];
  for (int i = threadIdx.x; i < 4096; i += 1024) {
    sl0[i] = lin0[i];
    sl1[i] = lin1[i];
    sf0[i] = fin0[i];
    sf1[i] = fin1[i];
  }
  for (int i = threadIdx.x; i < 1920; i += 1024) sc0[i] = c0w[i];
  for (int i = threadIdx.x; i < 1280; i += 1024) sc1[i] = c1w[i];
  __syncthreads();

  const int lane = threadIdx.x & 63;
  float* sb = sm + 16384 + (threadIdx.x >> 6) * 256;
  for (int n = blockIdx.x * 16 + (threadIdx.x >> 6); n < kN; n += 512 * 16) {
    const uint2 tu = tq[(size_t)n * 64 + lane];
    const float t_x = blo(tu.x), t_y = bhi(tu.x);
    const float t_z = blo(tu.y), t_w = bhi(tu.y);
    float avl = 0.f;
    if (lane < 10) avl = attrs[(size_t)n * 10 + lane];
    float b0 = 0.f, bx = 0.f, by = 0.f, bz = 0.f;
#pragma unroll
    for (int k = 0; k < 64; ++k) {
      const float w0 = sl0[k * 64 + lane];
      const float w1 = sl1[k * 64 + lane];
      b0 = fmaf(bcast(t_x, k), w0, b0);
      bx = fmaf(bcast(t_y, k), w1, bx);
      by = fmaf(bcast(t_z, k), w1, by);
      bz = fmaf(bcast(t_w, k), w1, bz);
    }
    float cw00 = 0.f, cw01 = 0.f, cw02 = 0.f, cw10 = 0.f, cw11 = 0.f;
#pragma unroll
    for (int a = 0; a < 10; ++a) {
      const float av = bcast(avl, a);
      cw00 = fmaf(av, sc0[a * 192 + lane], cw00);
      cw01 = fmaf(av, sc0[a * 192 + 64 + lane], cw01);
      cw02 = fmaf(av, sc0[a * 192 + 128 + lane], cw02);
      cw10 = fmaf(av, sc1[a * 128 + lane], cw10);
      cw11 = fmaf(av, sc1[a * 128 + 64 + lane], cw11);
    }
    const size_t pidx = (size_t)n * 64 + lane;
    const float scx = scout[pidx];
    const float scy = scout[(size_t)kPl + pidx];
    const float scz = scout[(size_t)2 * kPl + pidx];
    const float scw = scout[(size_t)3 * kPl + pidx];
    const float o0 = cw00 * b0 + cw01 * b0 * b0 +
                     cw02 * (bx * bx + by * by + bz * bz) + scx;
    const float o1x = cw10 * bx + cw11 * b0 * bx + scy;
    const float o1y = cw10 * by + cw11 * b0 * by + scz;
    const float o1z = cw10 * bz + cw11 * b0 * bz + scw;
    float f0 = 0.f, fx = 0.f, fy = 0.f, fz = 0.f;
#pragma unroll
    for (int k = 0; k < 64; ++k) {
      const float w0 = sf0[k * 64 + lane];
      const float w1 = sf1[k * 64 + lane];
      f0 = fmaf(bcast(o0, k), w0, f0);
      fx = fmaf(bcast(o1x, k), w1, fx);
      fy = fmaf(bcast(o1y, k), w1, fy);
      fz = fmaf(bcast(o1z, k), w1, fz);
    }
    sb[lane] = f0;
    sb[64 + 3 * lane] = fx;
    sb[64 + 3 * lane + 1] = fy;
    sb[64 + 3 * lane + 2] = fz;
    out[(size_t)n * 64 + lane] = *(const float4*)&sb[lane * 4];
  }
}

}  // namespace

extern "C" void kernel_launch(void* const* d_in, const int* in_sizes, int n_in,
                              void* d_out, int out_size, void* d_ws,
                              size_t ws_size, hipStream_t stream) {
  (void)in_sizes; (void)n_in; (void)out_size;
  const float* nf = (const float*)d_in[0];
  const float* attrs = (const float*)d_in[1];
  const float* sph = (const float*)d_in[2];
  const float* rb = (const float*)d_in[3];
  const int* ei = (const int*)d_in[4];
  const float* preW0 = (const float*)d_in[5];
  const float* preW1 = (const float*)d_in[6];
  const float* mW1 = (const float*)d_in[7];
  const float* mW2 = (const float*)d_in[8];
  const float* mW3 = (const float*)d_in[9];
  const float* lin0 = (const float*)d_in[10];
  const float* lin1 = (const float*)d_in[11];
  const float* c0w = (const float*)d_in[12];
  const float* c1w = (const float*)d_in[13];
  const float* scW0 = (const float*)d_in[14];
  const float* scW1 = (const float*)d_in[15];
  const float* fin0 = (const float*)d_in[16];
  const float* fin1 = (const float*)d_in[17];
  float4* out = (float4*)d_out;

  char* ws = (char*)d_ws;
  uint2* hq = (uint2*)ws;                      // 25.6MB bf16 h (region 51.2MB,
                                               // reused as scout after k_edge2)
  uint2* tq = (uint2*)(ws + 51200000);         // 25.6MB bf16 t (region 51.2MB)
  int* cnts = (int*)(ws + 102400000);          // 200KB
  int* starts = (int*)(ws + 102600000);        // 200KB (ends after scatter)
  int* eids = (int*)(ws + 102800000);          // 3.2MB -> ends 106.0MB
  unsigned short* xp = (unsigned short*)(ws + 106000000);  // 19.2MB bf16 x1
  uint32_t* wbuf = (uint32_t*)(ws + 125200000);
  float* scout = (float*)ws;  // 4 planar f32 planes (51.2MB total)

  // chunk sizing: 640B per slot of bf16 w (uncapped — R11/R14 best config)
  long long avail = (long long)ws_size - 125200000ll;
  long long cs64 = (avail > 0) ? avail / 640 : 0;
  if (cs64 > kE) cs64 = kE;
  const int chunkSlots = (int)(cs64 & ~15ll);
  const bool mfma = (chunkSlots >= 64000);

  hipMemsetAsync(cnts, 0, kN * sizeof(int), stream);
  k_pre<<<2048, 256, 0, stream>>>(nf, preW0, preW1, hq, xp);
  k_hist<<<(kE + 255) / 256, 256, 0, stream>>>(ei, cnts);
  k_scan<<<1, 1024, 0, stream>>>(cnts, starts);
  k_scatter<<<(kE + 255) / 256, 256, 0, stream>>>(ei, starts, eids);

  if (mfma) {
    hipMemsetAsync(tq, 0, (size_t)kN * 512, stream);
    int done = 0;
    while (done < kE) {
      const int cs = (kE - done < chunkSlots) ? (kE - done) : chunkSlots;
      const int tiles = cs / 16;
      k_mlp<<<768, 256, 0, stream>>>(rb, eids, mW1, mW2, mW3, wbuf,
                                     done / 16, tiles);
      k_edge2<<<512, 1024, 0, stream>>>(sph, ei, eids, starts, cnts, wbuf,
                                        hq, tq, done, done + cs);
      done += cs;
    }
  } else {
    hipFuncSetAttribute((const void*)k_edge,
                        hipFuncAttributeMaxDynamicSharedMemorySize, 12800 * 4);
    k_edge<<<1024, 512, 12800 * 4, stream>>>(rb, sph, ei, eids, starts, cnts,
                                             mW1, mW2, mW3, hq, tq);
  }

  hipFuncSetAttribute((const void*)k_sc2,
                      hipFuncAttributeMaxDynamicSharedMemorySize, 81920);
  k_sc2<<<196, 1024, 81920, stream>>>(nf, attrs, xp, scW0, scW1, scout);

  hipFuncSetAttribute((const void*)k_post,
                      hipFuncAttributeMaxDynamicSharedMemorySize, 20480 * 4);
  k_post<<<512, 1024, 20480 * 4, stream>>>(attrs, lin0, lin1, c0w, c1w,
                                           fin0, fin1, tq, scout, out);
}